// Round 9
// baseline (6311.317 us; speedup 1.0000x reference)
//
#include <hip/hip_runtime.h>

#define CB 4
#define CS 2048
#define CD 512
#define CH 8
#define CK 9
#define CDK 64
#define CBH 32

// total order matching jax.lax.top_k: larger value first; ties -> lower index
template <typename T>
__device__ __forceinline__ bool beats(T v, int j, T v2, int j2) {
    return (v > v2) || (v == v2 && j < j2);
}

// ---------------- W transpose (pure copy; enables coalesced strict proj) ----------------
__global__ __launch_bounds__(256) void k_transpose512(const float* __restrict__ W,
                                                      float* __restrict__ wt) {
    int idx = blockIdx.x * 256 + threadIdx.x;  // 262144 total
    int k = idx >> 9, n = idx & 511;
    wt[idx] = W[n * CD + k];  // wt[k][n] = W[n][k]
}

// ---------------- sgemm-model fp32 projection ----------------
// OpenBLAS sgemm emulation: per output element, sequential FMA over k ascending,
// K split into panels of Q=384 (Haswell/Zen SGEMM_DEFAULT_Q): panel partials in
// separate accumulators, combined with one rounded add; then one rounded bias add.
__global__ __launch_bounds__(256) void k_proj_sgemm(const float* __restrict__ x,
                                                    const float* __restrict__ wt,
                                                    const float* __restrict__ b,
                                                    float* __restrict__ out) {
    const int r = blockIdx.x;                        // 0..8191 (= bb*2048+s)
    const int n = blockIdx.y * 256 + threadIdx.x;    // 0..511
    const float* xr = x + (size_t)r * CD;
    float acc1 = 0.f;
#pragma unroll 1
    for (int k = 0; k < 384; ++k)
        acc1 = __fmaf_rn(xr[k], wt[k * CD + n], acc1);
    float acc2 = 0.f;
#pragma unroll 1
    for (int k = 384; k < CD; ++k)
        acc2 = __fmaf_rn(xr[k], wt[k * CD + n], acc2);
    float acc = __fadd_rn(acc1, acc2);   // C = panel1 + panel2 (one rounding)
    acc = __fadd_rn(acc, b[n]);          // + bias (one rounding)
    int bb = r >> 11, s = r & 2047, h = n >> 6, d = n & 63;
    out[(((size_t)(bb * CH + h) * CS + s) * CDK) + d] = acc;
}

// ---------------- strict fp32 L2-normalize per (bh, s) row of 64 channels ----------------
// np.linalg.norm axis=1 (outer-axis reduce): sequential d ascending, separate
// mul/add; sqrt_rn; kn = k / max(norm, 1e-12) per-element div_rn.
__global__ __launch_bounds__(256) void k_norm_strict(const float* __restrict__ raw,
                                                     float* __restrict__ outn) {
    size_t row = (size_t)blockIdx.x * 256 + threadIdx.x;  // 0..65535 (bh*2048+s)
    const float* p = raw + row * CDK;
    float ss = 0.f;
#pragma unroll 1
    for (int d = 0; d < CDK; ++d) ss = __fadd_rn(ss, __fmul_rn(p[d], p[d]));
    float nrm = __fsqrt_rn(ss);
    float mx = fmaxf(nrm, 1e-12f);
    float* o = outn + row * CDK;
#pragma unroll 1
    for (int d = 0; d < CDK; ++d) o[d] = __fdiv_rn(p[d], mx);
}

// ---------------- strict fp32 sim + top-9 (9-pass wave argmax, ties -> lower index) ----------------
// sim dot: numpy einsum strided scalar loop model — sequential d ascending,
// separate mul/add (baseline x86-64, no FMA).
__global__ __launch_bounds__(256) void k_topk9_strict(const float* __restrict__ kn,
                                                      const float* __restrict__ qn,
                                                      int* __restrict__ idx_out) {
    __shared__ float qLds[64][66];
    __shared__ float kLds[4][64];
    const int t = threadIdx.x;
    const int w = t >> 6;   // wave id 0..3
    const int l = t & 63;   // lane id
    const int i0 = blockIdx.x * 4;
    const int bh = blockIdx.y;
    const float* knb = kn + (size_t)bh * CS * CDK;
    const float* qnb = qn + (size_t)bh * CS * CDK;

    kLds[w][l] = knb[(size_t)(i0 + w) * CDK + l];

    float sv[32];
#pragma unroll 1
    for (int jt = 0; jt < 32; ++jt) {
        __syncthreads();
#pragma unroll
        for (int u2 = 0; u2 < 16; ++u2) {
            int f = u2 * 256 + t;
            int j = f >> 6, d = f & 63;
            qLds[j][d] = qnb[(size_t)(jt * 64 + j) * CDK + d];
        }
        __syncthreads();
        float a = 0.f;
#pragma unroll 1
        for (int d = 0; d < 64; ++d)
            a = __fadd_rn(a, __fmul_rn(kLds[w][d], qLds[l][d]));  // strict, seq, no FMA
        sv[jt] = fmaxf(a, 0.f);  // ReLU clamp BEFORE top-k (reference)
    }

    const int i = i0 + w;
#pragma unroll 1
    for (int p = 0; p < CK; ++p) {
        float bv = sv[0];
        int bj = l;
#pragma unroll
        for (int u = 1; u < 32; ++u) {
            int ju = u * 64 + l;
            if (beats(sv[u], ju, bv, bj)) { bv = sv[u]; bj = ju; }
        }
#pragma unroll
        for (int off = 1; off < 64; off <<= 1) {
            float ov = __shfl_xor(bv, off, 64);
            int oj = __shfl_xor(bj, off, 64);
            if (beats(ov, oj, bv, bj)) { bv = ov; bj = oj; }
        }
        if (l == 0) idx_out[((size_t)bh * CS + i) * CK + p] = bj;
        if ((bj & 63) == l) {
            int wu = bj >> 6;
#pragma unroll
            for (int u = 0; u < 32; ++u)
                if (u == wu) sv[u] = -1.f;
        }
    }
}

// ---------------- fp64 projection (v path), out fp32 [BH][S][DK] ----------------
__global__ __launch_bounds__(256) void k_proj_v(const float* __restrict__ A,
                                                const float* __restrict__ W,
                                                const float* __restrict__ bias,
                                                float* __restrict__ outf) {
    __shared__ double AT[16][68];
    __shared__ double WT[16][68];
    const int t = threadIdx.x;
    const int tm = t >> 4, tn = t & 15;
    const int r0 = blockIdx.x * 64;
    const int n0 = blockIdx.y * 64;  // one head per block
    double acc[4][4];
#pragma unroll
    for (int i = 0; i < 4; ++i)
#pragma unroll
        for (int j = 0; j < 4; ++j) acc[i][j] = 0.0;

    for (int k0 = 0; k0 < CD; k0 += 16) {
        {
            int row = t >> 2, kq = t & 3;
            float4 ga = *(const float4*)&A[(r0 + row) * CD + k0 + kq * 4];
            AT[kq * 4 + 0][row] = (double)ga.x; AT[kq * 4 + 1][row] = (double)ga.y;
            AT[kq * 4 + 2][row] = (double)ga.z; AT[kq * 4 + 3][row] = (double)ga.w;
            float4 gw = *(const float4*)&W[(n0 + row) * CD + k0 + kq * 4];
            WT[kq * 4 + 0][row] = (double)gw.x; WT[kq * 4 + 1][row] = (double)gw.y;
            WT[kq * 4 + 2][row] = (double)gw.z; WT[kq * 4 + 3][row] = (double)gw.w;
        }
        __syncthreads();
#pragma unroll
        for (int k = 0; k < 16; ++k) {
            double av[4], bv[4];
#pragma unroll
            for (int i = 0; i < 4; ++i) av[i] = AT[k][tm * 4 + i];
#pragma unroll
            for (int j = 0; j < 4; ++j) bv[j] = WT[k][tn * 4 + j];
#pragma unroll
            for (int i = 0; i < 4; ++i)
#pragma unroll
                for (int j = 0; j < 4; ++j) acc[i][j] += av[i] * bv[j];
        }
        __syncthreads();
    }

#pragma unroll
    for (int j = 0; j < 4; ++j) {
        double bj = (double)bias[n0 + tn * 4 + j];
#pragma unroll
        for (int i = 0; i < 4; ++i) acc[i][j] += bj;
    }

    const int hA = n0 >> 6;
#pragma unroll
    for (int i = 0; i < 4; ++i) {
        int r = r0 + tm * 4 + i;
        int b = r >> 11, s = r & 2047;
        float* o = &outf[(((size_t)(b * CH + hA) * CS + s) * CDK) + tn * 4];
        o[0] = (float)acc[i][0]; o[1] = (float)acc[i][1];
        o[2] = (float)acc[i][2]; o[3] = (float)acc[i][3];
    }
}

// ---------------- gather + grouped conv + scramble store (verified r5) ----------------
__global__ __launch_bounds__(256) void k_conv2(const float* __restrict__ v,
                                               const int* __restrict__ idxw,
                                               const float* __restrict__ cw,
                                               const float* __restrict__ cb,
                                               float* __restrict__ y2) {
    __shared__ float vLds[4][CK][64];  // [wave(i)][kk][cin]
    __shared__ float wS[64][64];       // [cin][co] for current kk
    const int t = threadIdx.x;
    const int w = t >> 6;
    const int co = t & 63;
    const int bh = blockIdx.y;
    const int i = blockIdx.x * 4 + w;

#pragma unroll
    for (int kk = 0; kk < CK; ++kk) {
        int j = idxw[((size_t)bh * CS + i) * CK + kk];
        vLds[w][kk][co] = v[((size_t)bh * CS + j) * CDK + co];
    }

    float acc = cb[co];
    for (int kk = 0; kk < CK; ++kk) {
        __syncthreads();
#pragma unroll
        for (int u = 0; u < 16; ++u) {
            int lin = u * 256 + t;
            int cc = lin & 63, cin = lin >> 6;
            wS[cin][cc] = cw[(cc * CDK + cin) * CK + kk];
        }
        __syncthreads();
#pragma unroll 8
        for (int cin = 0; cin < 64; ++cin)
            acc = fmaf(wS[cin][co], vLds[w][kk][cin], acc);
    }

    int b = bh >> 3, h = bh & 7;
    int s2 = (i & 31) * 64 + co;
    int d2 = i >> 5;
    y2[((size_t)b * CS + s2) * CD + h * CDK + d2] = acc;
}

// ---------------- out = y2 @ Wo^T + b, 64x64 tile, 4x4/thread (verified r5) ----------------
__global__ __launch_bounds__(256) void k_wo(const float* __restrict__ A,
                                            const float* __restrict__ W,
                                            const float* __restrict__ bias,
                                            float* __restrict__ out) {
    __shared__ float As[32][68];
    __shared__ float Ws[32][68];
    const int t = threadIdx.x;
    const int tm = t >> 4, tn = t & 15;
    const int m0 = blockIdx.x * 64;
    const int n0 = blockIdx.y * 64;
    float acc[4][4];
#pragma unroll
    for (int i = 0; i < 4; ++i)
#pragma unroll
        for (int j = 0; j < 4; ++j) acc[i][j] = 0.f;

    for (int k0 = 0; k0 < CD; k0 += 32) {
#pragma unroll
        for (int u = 0; u < 2; ++u) {
            int lin = u * 1024 + t * 4;
            int m = lin >> 5, kq = lin & 31;
            float4 ga = *(const float4*)&A[(size_t)(m0 + m) * CD + k0 + kq];
            As[kq + 0][m] = ga.x; As[kq + 1][m] = ga.y;
            As[kq + 2][m] = ga.z; As[kq + 3][m] = ga.w;
            float4 gw = *(const float4*)&W[(size_t)(n0 + m) * CD + k0 + kq];
            Ws[kq + 0][m] = gw.x; Ws[kq + 1][m] = gw.y;
            Ws[kq + 2][m] = gw.z; Ws[kq + 3][m] = gw.w;
        }
        __syncthreads();
#pragma unroll
        for (int k = 0; k < 32; ++k) {
            float av[4], bv[4];
#pragma unroll
            for (int i = 0; i < 4; ++i) av[i] = As[k][tm * 4 + i];
#pragma unroll
            for (int j = 0; j < 4; ++j) bv[j] = Ws[k][tn * 4 + j];
#pragma unroll
            for (int i = 0; i < 4; ++i)
#pragma unroll
                for (int j = 0; j < 4; ++j) acc[i][j] = fmaf(av[i], bv[j], acc[i][j]);
        }
        __syncthreads();
    }

#pragma unroll
    for (int i = 0; i < 4; ++i)
#pragma unroll
        for (int j = 0; j < 4; ++j)
            out[(size_t)(m0 + tm * 4 + i) * CD + n0 + tn * 4 + j] =
                acc[i][j] + bias[n0 + tn * 4 + j];
}

// ---------------- launch ----------------
extern "C" void kernel_launch(void* const* d_in, const int* in_sizes, int n_in,
                              void* d_out, int out_size, void* d_ws, size_t ws_size,
                              hipStream_t stream) {
    (void)in_sizes; (void)n_in; (void)out_size; (void)ws_size;
    const float* x      = (const float*)d_in[0];
    const float* Wq_w   = (const float*)d_in[1];
    const float* Wq_b   = (const float*)d_in[2];
    const float* Wk_w   = (const float*)d_in[3];
    const float* Wk_b   = (const float*)d_in[4];
    const float* Wv_w   = (const float*)d_in[5];
    const float* Wv_b   = (const float*)d_in[6];
    const float* Wo_w   = (const float*)d_in[7];
    const float* Wo_b   = (const float*)d_in[8];
    const float* conv_w = (const float*)d_in[9];
    const float* conv_b = (const float*)d_in[10];
    float* out = (float*)d_out;

    // ws layout (bytes): qraw 0-16M (y2 overlays later), kraw 16-32M,
    // qn 32-48M, kn 48-64M, vv 64-80M, idxw 80-82.3M, wtq 83-84M, wtk 84-85M
    char* wsb = (char*)d_ws;
    float* qraw = (float*)(wsb);
    float* kraw = (float*)(wsb + (size_t)16 * 1024 * 1024);
    float* qn   = (float*)(wsb + (size_t)32 * 1024 * 1024);
    float* kn   = (float*)(wsb + (size_t)48 * 1024 * 1024);
    float* vv   = (float*)(wsb + (size_t)64 * 1024 * 1024);
    int*  idxw  = (int*)  (wsb + (size_t)80 * 1024 * 1024);
    float* wtq  = (float*)(wsb + (size_t)83 * 1024 * 1024);
    float* wtk  = (float*)(wsb + (size_t)84 * 1024 * 1024);
    float* y2   = (float*)(wsb);  // overlays qraw (dead after k_norm_strict)

    k_transpose512<<<1024, 256, 0, stream>>>(Wq_w, wtq);
    k_transpose512<<<1024, 256, 0, stream>>>(Wk_w, wtk);
    dim3 gps(8192, 2);
    k_proj_sgemm<<<gps, 256, 0, stream>>>(x, wtq, Wq_b, qraw);
    k_proj_sgemm<<<gps, 256, 0, stream>>>(x, wtk, Wk_b, kraw);
    k_norm_strict<<<256, 256, 0, stream>>>(qraw, qn);
    k_norm_strict<<<256, 256, 0, stream>>>(kraw, kn);
    k_proj_v<<<dim3(128, 8), 256, 0, stream>>>(x, Wv_w, Wv_b, vv);
    k_topk9_strict<<<dim3(512, 32), 256, 0, stream>>>(kn, qn, idxw);
    k_conv2<<<dim3(512, 32), 256, 0, stream>>>(vv, idxw, conv_w, conv_b, y2);
    k_wo<<<dim3(128, 8), 256, 0, stream>>>(y2, Wo_w, Wo_b, out);
}